// Round 1
// baseline (6219.505 us; speedup 1.0000x reference)
//
#include <hip/hip_runtime.h>
#include <type_traits>

typedef unsigned short ushort_t;
typedef unsigned int   uint_t;

constexpr int Bn = 4, Tn = 1024, Cn = 2048, NH = 16, HS = 128;
constexpr int NLQ = 1536, NLKV = 512, DHR = 64;
constexpr int BT = Bn * Tn;
constexpr float ATT_SCALE = 0.07216878364870323f; // 1/sqrt(HS+DHR)=1/sqrt(192)

__device__ __forceinline__ ushort_t f2bf(float f) {
    uint_t u = __float_as_uint(f);
    u += 0x7fffu + ((u >> 16) & 1u);   // round-to-nearest-even
    return (ushort_t)(u >> 16);
}

// ---------------------------------------------------------------------------
// Tiled f32 GEMM: C[M,N] = A[M,K] * B, where B is NN (B[k*ldb+n]) or
// NT (B[n*ldb+k]). Batched via element strides sA/sB/sC. All dims must be
// multiples of tile sizes (true for every call here). OutT float or bf16(ushort).
// ---------------------------------------------------------------------------
template<int BM, int BN, int BK, int TM, int TN, bool BTRANS, typename OutT>
__global__ __launch_bounds__(256) void gemm_f32(
    const float* __restrict__ A, const float* __restrict__ Bp, OutT* __restrict__ Cp,
    int K, int lda, int ldb, int ldc, long sA, long sB, long sC)
{
    static_assert(BK == 16, "loader assumes BK=16");
    static_assert((BM / TM) * (BN / TN) == 256, "256 threads");
    const float* Ab = A  + (long)blockIdx.z * sA;
    const float* Bx = Bp + (long)blockIdx.z * sB;
    OutT*        Cb = Cp + (long)blockIdx.z * sC;

    __shared__ float As[BK][BM + 4];
    __shared__ float Bs[BK][BN + 4];

    const int tid = threadIdx.x;
    const int tx = tid % (BN / TN);      // 16 col groups
    const int ty = tid / (BN / TN);
    const int m0 = blockIdx.y * BM, n0 = blockIdx.x * BN;

    float acc[TM][TN] = {};

    for (int k0 = 0; k0 < K; k0 += BK) {
        // A tile (BM x BK), stored transposed As[k][m]
        #pragma unroll
        for (int i = 0; i < BM * BK / 1024; ++i) {
            int chunk = tid + i * 256;
            int row = chunk >> 2;        // BK/4 = 4 float4 chunks per row
            int kq  = chunk & 3;
            float4 v = *(const float4*)&Ab[(long)(m0 + row) * lda + k0 + kq * 4];
            As[kq * 4 + 0][row] = v.x; As[kq * 4 + 1][row] = v.y;
            As[kq * 4 + 2][row] = v.z; As[kq * 4 + 3][row] = v.w;
        }
        if constexpr (BTRANS) {
            #pragma unroll
            for (int i = 0; i < BN * BK / 1024; ++i) {
                int chunk = tid + i * 256;
                int row = chunk >> 2;
                int kq  = chunk & 3;
                float4 v = *(const float4*)&Bx[(long)(n0 + row) * ldb + k0 + kq * 4];
                Bs[kq * 4 + 0][row] = v.x; Bs[kq * 4 + 1][row] = v.y;
                Bs[kq * 4 + 2][row] = v.z; Bs[kq * 4 + 3][row] = v.w;
            }
        } else {
            #pragma unroll
            for (int i = 0; i < BN * BK / 1024; ++i) {
                int chunk = tid + i * 256;
                int krow = chunk / (BN / 4);
                int nq   = chunk % (BN / 4);
                *(float4*)&Bs[krow][nq * 4] =
                    *(const float4*)&Bx[(long)(k0 + krow) * ldb + n0 + nq * 4];
            }
        }
        __syncthreads();

        #pragma unroll
        for (int kk = 0; kk < BK; ++kk) {
            float a[TM], bv[TN];
            #pragma unroll
            for (int i = 0; i < TM; ++i) a[i] = As[kk][ty * TM + i];
            // split-half B cols: avoids 4-way bank conflict from 8-float stride
            #pragma unroll
            for (int j = 0; j < TN; ++j) {
                int half = j / (TN / 2), jj = j % (TN / 2);
                bv[j] = Bs[kk][half * (BN / 2) + tx * (TN / 2) + jj];
            }
            #pragma unroll
            for (int i = 0; i < TM; ++i)
                #pragma unroll
                for (int j = 0; j < TN; ++j)
                    acc[i][j] += a[i] * bv[j];
        }
        __syncthreads();
    }

    #pragma unroll
    for (int i = 0; i < TM; ++i) {
        long rbase = (long)(m0 + ty * TM + i) * ldc + n0;
        #pragma unroll
        for (int half = 0; half < 2; ++half) {
            long cbase = rbase + half * (BN / 2) + tx * (TN / 2);
            if constexpr (std::is_same<OutT, float>::value) {
                #pragma unroll
                for (int jj = 0; jj < TN / 2; ++jj)
                    Cb[cbase + jj] = acc[i][half * (TN / 2) + jj];
            } else {
                // bf16 pack, TN/2 == 4 -> one 8B store
                ushort_t pk[4];
                #pragma unroll
                for (int jj = 0; jj < 4; ++jj) pk[jj] = f2bf(acc[i][half * (TN / 2) + jj]);
                uint2 u;
                u.x = (uint_t)pk[0] | ((uint_t)pk[1] << 16);
                u.y = (uint_t)pk[2] | ((uint_t)pk[3] << 16);
                *(uint2*)&Cb[cbase] = u;
            }
        }
    }
}

// ---------------------------------------------------------------------------
// RoPE kernels (in-place)
// ---------------------------------------------------------------------------
__global__ void rope_kr_kernel(float* __restrict__ krb,
                               const float* __restrict__ cosT, const float* __restrict__ sinT) {
    int p = blockIdx.x * 256 + threadIdx.x;          // BT*32 pairs
    if (p >= BT * 32) return;
    int bt = p >> 5, i = p & 31;
    int t = bt & (Tn - 1);
    float c = cosT[t * 32 + i], s = sinT[t * 32 + i];
    float re = krb[bt * 64 + 2 * i], im = krb[bt * 64 + 2 * i + 1];
    krb[bt * 64 + 2 * i]     = re * c - im * s;
    krb[bt * 64 + 2 * i + 1] = re * s + im * c;
}

__global__ void rope_qr_kernel(float* __restrict__ qrb,
                               const float* __restrict__ cosT, const float* __restrict__ sinT) {
    int p = blockIdx.x * 256 + threadIdx.x;          // BT*NH*32 pairs
    if (p >= BT * 512) return;
    int bt = p >> 9, rem = p & 511;
    int hh = rem >> 5, i = rem & 31;
    int t = bt & (Tn - 1);
    float c = cosT[t * 32 + i], s = sinT[t * 32 + i];
    long base = (long)bt * (NH * DHR) + hh * DHR + 2 * i;
    float re = qrb[base], im = qrb[base + 1];
    qrb[base]     = re * c - im * s;
    qrb[base + 1] = re * s + im * c;
}

// ---------------------------------------------------------------------------
// Flash MLA: per (q-tile of 16, head, batch). Scores = q_abs . c_kv + q_r . k_r,
// online softmax, y_lat accum in regs, fused v_eff (Mt) projection epilogue.
// ---------------------------------------------------------------------------
__global__ __launch_bounds__(256) void flash_mla(
    const ushort_t* __restrict__ qabs,  // [NH][BT][512] bf16
    const float*    __restrict__ qr,    // [BT][1024] post-rope
    const float*    __restrict__ ckv,   // [BT][512]
    const float*    __restrict__ kr,    // [BT][64]  post-rope
    const float*    __restrict__ Mt,    // [2048][512]  (v_eff^T rows)
    float*          __restrict__ out)   // [BT][2048]
{
    constexpr int QT = 16, KT = 16, LS = 580;   // LS odd-ish stride: kills 576-float bank aliasing
    __shared__ float q_s[QT * LS];
    __shared__ float kv_s[KT * LS];
    __shared__ float P_s[QT * 20];

    const int tid = threadIdx.x;
    const int t0 = blockIdx.x * QT;
    const int h  = blockIdx.y;
    const int b  = blockIdx.z;
    const long bt0 = (long)b * Tn + t0;

    // stage Q tile: 512 bf16 (q_abs) + 64 f32 (q_r) per row
    #pragma unroll
    for (int it = 0; it < 4; ++it) {
        int chunk = tid + it * 256;           // 1024 chunks of 8 bf16
        int row = chunk >> 6, c8 = chunk & 63;
        uint4 v = *(const uint4*)&qabs[((long)h * BT + bt0 + row) * 512 + c8 * 8];
        float* dst = &q_s[row * LS + c8 * 8];
        const uint_t* w = (const uint_t*)&v;
        #pragma unroll
        for (int j = 0; j < 4; ++j) {
            dst[2 * j]     = __uint_as_float(w[j] << 16);
            dst[2 * j + 1] = __uint_as_float(w[j] & 0xffff0000u);
        }
    }
    {
        int row = tid >> 4, c4 = tid & 15;
        *(float4*)&q_s[row * LS + 512 + c4 * 4] =
            *(const float4*)&qr[(bt0 + row) * (NH * DHR) + h * DHR + c4 * 4];
    }

    const int r = tid >> 4, sc = tid & 15;
    float m = -INFINITY, l = 0.f;
    float y[32];
    #pragma unroll
    for (int j = 0; j < 32; ++j) y[j] = 0.f;

    for (int s0 = 0; s0 <= t0; s0 += KT) {
        __syncthreads();   // (iter0: Q writes visible) + protect kv_s vs prev PV reads
        #pragma unroll
        for (int it = 0; it < 8; ++it) {
            int chunk = tid + it * 256;       // 2048 float4 chunks
            int row = chunk >> 7, c4 = chunk & 127;
            *(float4*)&kv_s[row * LS + c4 * 4] =
                *(const float4*)&ckv[((long)b * Tn + s0 + row) * 512 + c4 * 4];
        }
        {
            int row = tid >> 4, c4 = tid & 15;
            *(float4*)&kv_s[row * LS + 512 + c4 * 4] =
                *(const float4*)&kr[((long)b * Tn + s0 + row) * 64 + c4 * 4];
        }
        __syncthreads();

        // scores: thread (r, sc) -> S[r][sc], 576-d dot
        float sv = 0.f;
        {
            const float* qp = &q_s[r * LS];
            const float* kp = &kv_s[sc * LS];
            #pragma unroll 9
            for (int c = 0; c < 576; c += 4) {
                float4 qa = *(const float4*)&qp[c];
                float4 kb = *(const float4*)&kp[c];
                sv += qa.x * kb.x + qa.y * kb.y + qa.z * kb.z + qa.w * kb.w;
            }
        }
        sv *= ATT_SCALE;
        if (s0 + sc > t0 + r) sv = -INFINITY;   // causal

        float smax = sv;
        #pragma unroll
        for (int off = 8; off >= 1; off >>= 1)
            smax = fmaxf(smax, __shfl_xor(smax, off));
        float mnew = fmaxf(m, smax);
        float corr = __expf(m - mnew);
        float p = __expf(sv - mnew);
        float rs = p;
        #pragma unroll
        for (int off = 8; off >= 1; off >>= 1)
            rs += __shfl_xor(rs, off);
        l = l * corr + rs;
        m = mnew;
        P_s[r * 20 + sc] = p;
        __syncthreads();

        // PV: thread (r, sc) owns y cols sc + 16j
        float pv[KT];
        #pragma unroll
        for (int s = 0; s < KT; ++s) pv[s] = P_s[r * 20 + s];
        #pragma unroll
        for (int j = 0; j < 32; ++j) y[j] *= corr;
        #pragma unroll 2
        for (int s = 0; s < KT; ++s) {
            const float* kvp = &kv_s[s * LS + sc];
            float ps = pv[s];
            #pragma unroll
            for (int j = 0; j < 32; ++j) y[j] += ps * kvp[16 * j];
        }
    }

    // epilogue: normalize, stage y_lat tile into q_s, project through Mt
    float invl = 1.f / l;
    __syncthreads();
    #pragma unroll
    for (int j = 0; j < 32; ++j) q_s[r * LS + sc + 16 * j] = y[j] * invl;
    __syncthreads();

    const int r2 = tid & 15, dg = tid >> 4;   // row r2, output col group dg*8
    float acc[8];
    #pragma unroll
    for (int j = 0; j < 8; ++j) acc[j] = 0.f;
    const float* yrow = &q_s[r2 * LS];
    const float* mrow = &Mt[(long)(h * HS + dg * 8) * 512];
    for (int k = 0; k < 512; k += 4) {
        float4 y4 = *(const float4*)&yrow[k];
        #pragma unroll
        for (int j = 0; j < 8; ++j) {
            float4 m4 = *(const float4*)&mrow[(long)j * 512 + k];
            acc[j] += y4.x * m4.x + y4.y * m4.y + y4.z * m4.z + y4.w * m4.w;
        }
    }
    float* op = &out[(bt0 + r2) * Cn + h * HS + dg * 8];
    *(float4*)&op[0] = make_float4(acc[0], acc[1], acc[2], acc[3]);
    *(float4*)&op[4] = make_float4(acc[4], acc[5], acc[6], acc[7]);
}

// ---------------------------------------------------------------------------
extern "C" void kernel_launch(void* const* d_in, const int* in_sizes, int n_in,
                              void* d_out, int out_size, void* d_ws, size_t ws_size,
                              hipStream_t stream)
{
    (void)in_sizes; (void)n_in; (void)out_size; (void)ws_size;
    const float* x     = (const float*)d_in[0];
    const float* cosT  = (const float*)d_in[1];
    const float* sinT  = (const float*)d_in[2];
    const float* W_dq  = (const float*)d_in[3];   // [1536][2048]
    const float* W_uq  = (const float*)d_in[4];   // [2048][1536] (flat-reinterpreted)
    const float* W_dkv = (const float*)d_in[5];   // [512][2048]
    const float* W_uk  = (const float*)d_in[6];   // [2048][512]
    const float* W_uv  = (const float*)d_in[7];   // [2048][512]
    const float* W_qr  = (const float*)d_in[8];   // [1024][1536]
    const float* W_kr  = (const float*)d_in[9];   // [64][2048]
    const float* W_o   = (const float*)d_in[10];  // [2048][2048]
    float* out = (float*)d_out;

    // workspace layout (~173 MB)
    float* c_q  = (float*)d_ws;                         // [BT][1536]
    float* c_kv = c_q  + (long)BT * NLQ;                // [BT][512]
    float* krb  = c_kv + (long)BT * NLKV;               // [BT][64]
    float* qrb  = krb  + (long)BT * DHR;                // [BT][1024]
    float* keff = qrb  + (long)BT * NH * DHR;           // [16][1536][512]
    float* Mt   = keff + (long)NH * NLQ * NLKV;         // [2048][512]
    ushort_t* qabs = (ushort_t*)(Mt + (long)Cn * NLKV); // bf16 [16][BT][512]

    dim3 blk(256, 1, 1);

    // c_q = X @ W_dq^T            (4096x1536, K=2048)
    gemm_f32<128,128,16,8,8,true,float><<<dim3(NLQ/128, BT/128, 1), blk, 0, stream>>>(
        x, W_dq, c_q, Cn, Cn, Cn, NLQ, 0, 0, 0);
    // c_kv = X @ W_dkv^T          (4096x512, K=2048)
    gemm_f32<128,128,16,8,8,true,float><<<dim3(NLKV/128, BT/128, 1), blk, 0, stream>>>(
        x, W_dkv, c_kv, Cn, Cn, Cn, NLKV, 0, 0, 0);
    // c_kr = X @ W_kr^T           (4096x64, K=2048)
    gemm_f32<64,64,16,4,4,true,float><<<dim3(1, BT/64, 1), blk, 0, stream>>>(
        x, W_kr, krb, Cn, Cn, Cn, DHR, 0, 0, 0);
    rope_kr_kernel<<<dim3(BT*32/256), blk, 0, stream>>>(krb, cosT, sinT);
    // c_qr = c_q @ W_qr^T         (4096x1024, K=1536)
    gemm_f32<128,128,16,8,8,true,float><<<dim3(NH*DHR/128, BT/128, 1), blk, 0, stream>>>(
        c_q, W_qr, qrb, NLQ, NLQ, NLQ, NH*DHR, 0, 0, 0);
    rope_qr_kernel<<<dim3(BT*512/256), blk, 0, stream>>>(qrb, cosT, sinT);
    // k_eff[h] = Wuq_h(1536x128, lda 2048, off h*128) @ Wuk_h(128x512)  batched 16
    gemm_f32<128,128,16,8,8,false,float><<<dim3(NLKV/128, NLQ/128, NH), blk, 0, stream>>>(
        W_uq, W_uk, keff, HS, Cn, NLKV, NLKV,
        (long)HS, (long)HS*NLKV, (long)NLQ*NLKV);
    // Mt = W_o @ W_uv             (2048x512, K=2048)  [v_eff[h,k,d] = Mt[h*128+d, k]]
    gemm_f32<128,128,16,8,8,false,float><<<dim3(NLKV/128, Cn/128, 1), blk, 0, stream>>>(
        W_o, W_uv, Mt, Cn, Cn, NLKV, NLKV, 0, 0, 0);
    // q_abs[h] = c_q @ k_eff[h]   (4096x512, K=1536) batched 16, bf16 out
    gemm_f32<128,128,16,8,8,false,ushort_t><<<dim3(NLKV/128, BT/128, NH), blk, 0, stream>>>(
        c_q, keff, qabs, NLQ, NLQ, NLKV, NLKV,
        0, (long)NLQ*NLKV, (long)BT*NLKV);
    // fused flash attention + output projection
    flash_mla<<<dim3(Tn/16, NH, Bn), blk, 0, stream>>>(qabs, qrb, c_kv, krb, Mt, out);
}

// Round 2
// 3181.272 us; speedup vs baseline: 1.9550x; 1.9550x over previous
//
#include <hip/hip_runtime.h>
#include <type_traits>

typedef unsigned short ushort_t;
typedef unsigned int   uint_t;
typedef __attribute__((ext_vector_type(8))) short bf16x8;
typedef __attribute__((ext_vector_type(4))) float f32x4;

constexpr int Bn = 4, Tn = 1024, Cn = 2048, NH = 16, HS = 128;
constexpr int NLQ = 1536, NLKV = 512, DHR = 64;
constexpr int BT = Bn * Tn;
constexpr float ATT_SCALE = 0.07216878364870323f; // 1/sqrt(192)
constexpr float LOG2E = 1.4426950408889634f;

__device__ __forceinline__ ushort_t f2bf(float f) {
    uint_t u = __float_as_uint(f);
    u += 0x7fffu + ((u >> 16) & 1u);   // RNE
    return (ushort_t)(u >> 16);
}

// ---------------------------------------------------------------------------
// Tiled f32 GEMM (unchanged from round 1): C[M,N] = A[M,K] * B (NN or NT).
// ---------------------------------------------------------------------------
template<int BM, int BN, int BK, int TM, int TN, bool BTRANS, typename OutT>
__global__ __launch_bounds__(256) void gemm_f32(
    const float* __restrict__ A, const float* __restrict__ Bp, OutT* __restrict__ Cp,
    int K, int lda, int ldb, int ldc, long sA, long sB, long sC)
{
    static_assert(BK == 16, "loader assumes BK=16");
    static_assert((BM / TM) * (BN / TN) == 256, "256 threads");
    const float* Ab = A  + (long)blockIdx.z * sA;
    const float* Bx = Bp + (long)blockIdx.z * sB;
    OutT*        Cb = Cp + (long)blockIdx.z * sC;

    __shared__ float As[BK][BM + 4];
    __shared__ float Bs[BK][BN + 4];

    const int tid = threadIdx.x;
    const int tx = tid % (BN / TN);
    const int ty = tid / (BN / TN);
    const int m0 = blockIdx.y * BM, n0 = blockIdx.x * BN;

    float acc[TM][TN] = {};

    for (int k0 = 0; k0 < K; k0 += BK) {
        #pragma unroll
        for (int i = 0; i < BM * BK / 1024; ++i) {
            int chunk = tid + i * 256;
            int row = chunk >> 2;
            int kq  = chunk & 3;
            float4 v = *(const float4*)&Ab[(long)(m0 + row) * lda + k0 + kq * 4];
            As[kq * 4 + 0][row] = v.x; As[kq * 4 + 1][row] = v.y;
            As[kq * 4 + 2][row] = v.z; As[kq * 4 + 3][row] = v.w;
        }
        if constexpr (BTRANS) {
            #pragma unroll
            for (int i = 0; i < BN * BK / 1024; ++i) {
                int chunk = tid + i * 256;
                int row = chunk >> 2;
                int kq  = chunk & 3;
                float4 v = *(const float4*)&Bx[(long)(n0 + row) * ldb + k0 + kq * 4];
                Bs[kq * 4 + 0][row] = v.x; Bs[kq * 4 + 1][row] = v.y;
                Bs[kq * 4 + 2][row] = v.z; Bs[kq * 4 + 3][row] = v.w;
            }
        } else {
            #pragma unroll
            for (int i = 0; i < BN * BK / 1024; ++i) {
                int chunk = tid + i * 256;
                int krow = chunk / (BN / 4);
                int nq   = chunk % (BN / 4);
                *(float4*)&Bs[krow][nq * 4] =
                    *(const float4*)&Bx[(long)(k0 + krow) * ldb + n0 + nq * 4];
            }
        }
        __syncthreads();

        #pragma unroll
        for (int kk = 0; kk < BK; ++kk) {
            float a[TM], bv[TN];
            #pragma unroll
            for (int i = 0; i < TM; ++i) a[i] = As[kk][ty * TM + i];
            #pragma unroll
            for (int j = 0; j < TN; ++j) {
                int half = j / (TN / 2), jj = j % (TN / 2);
                bv[j] = Bs[kk][half * (BN / 2) + tx * (TN / 2) + jj];
            }
            #pragma unroll
            for (int i = 0; i < TM; ++i)
                #pragma unroll
                for (int j = 0; j < TN; ++j)
                    acc[i][j] += a[i] * bv[j];
        }
        __syncthreads();
    }

    #pragma unroll
    for (int i = 0; i < TM; ++i) {
        long rbase = (long)(m0 + ty * TM + i) * ldc + n0;
        #pragma unroll
        for (int half = 0; half < 2; ++half) {
            long cbase = rbase + half * (BN / 2) + tx * (TN / 2);
            if constexpr (std::is_same<OutT, float>::value) {
                #pragma unroll
                for (int jj = 0; jj < TN / 2; ++jj)
                    Cb[cbase + jj] = acc[i][half * (TN / 2) + jj];
            } else {
                ushort_t pk[4];
                #pragma unroll
                for (int jj = 0; jj < 4; ++jj) pk[jj] = f2bf(acc[i][half * (TN / 2) + jj]);
                uint2 u;
                u.x = (uint_t)pk[0] | ((uint_t)pk[1] << 16);
                u.y = (uint_t)pk[2] | ((uint_t)pk[3] << 16);
                *(uint2*)&Cb[cbase] = u;
            }
        }
    }
}

// ---------------------------------------------------------------------------
// RoPE: read f32 GEMM output, write roped bf16 into the tails of kfull/qfull
// ---------------------------------------------------------------------------
__global__ void rope_kr_kernel(const float* __restrict__ krb, ushort_t* __restrict__ kfull,
                               const float* __restrict__ cosT, const float* __restrict__ sinT) {
    int p = blockIdx.x * 256 + threadIdx.x;          // BT*32 pairs
    if (p >= BT * 32) return;
    int bt = p >> 5, i = p & 31;
    int t = bt & (Tn - 1);
    float c = cosT[t * 32 + i], s = sinT[t * 32 + i];
    float re = krb[bt * 64 + 2 * i], im = krb[bt * 64 + 2 * i + 1];
    float o0 = re * c - im * s, o1 = re * s + im * c;
    uint_t u = (uint_t)f2bf(o0) | ((uint_t)f2bf(o1) << 16);
    *(uint_t*)&kfull[(long)bt * 576 + 512 + 2 * i] = u;
}

__global__ void rope_qr_kernel(const float* __restrict__ qrb, ushort_t* __restrict__ qfull,
                               const float* __restrict__ cosT, const float* __restrict__ sinT) {
    int p = blockIdx.x * 256 + threadIdx.x;          // BT*NH*32 pairs
    if (p >= BT * 512) return;
    int bt = p >> 9, rem = p & 511;
    int hh = rem >> 5, i = rem & 31;
    int t = bt & (Tn - 1);
    float c = cosT[t * 32 + i], s = sinT[t * 32 + i];
    long src = (long)bt * (NH * DHR) + hh * DHR + 2 * i;
    float re = qrb[src], im = qrb[src + 1];
    float o0 = re * c - im * s, o1 = re * s + im * c;
    uint_t u = (uint_t)f2bf(o0) | ((uint_t)f2bf(o1) << 16);
    *(uint_t*)&qfull[((long)hh * BT + bt) * 576 + 512 + 2 * i] = u;
}

// ---------------------------------------------------------------------------
// Transpose c_kv (cols 0..511 of kfull) into ckvT[b][c][t] (bf16)
// ---------------------------------------------------------------------------
__global__ void transpose_ckv(const ushort_t* __restrict__ kfull, ushort_t* __restrict__ ckvT) {
    int idx = blockIdx.x * 256 + threadIdx.x;        // 4*128*512
    int c = idx & 511, rest = idx >> 9;
    int t8 = rest & 127, b = rest >> 7;
    ushort_t v[8];
    #pragma unroll
    for (int j = 0; j < 8; ++j)
        v[j] = kfull[((long)b * Tn + t8 * 8 + j) * 576 + c];
    *(uint4*)&ckvT[((long)b * 512 + c) * Tn + t8 * 8] = *(const uint4*)v;
}

// ---------------------------------------------------------------------------
// MFMA flash MLA. Block: 64 q-rows x 1 head x 1 batch; 4 waves (16 rows each).
// S = Q(576) . K^T via mfma_f32_16x16x32_bf16; online softmax on f32 acc;
// P -> LDS (bf16) -> A-frags; PV with V B-frags straight from ckvT (L2);
// fused epilogue y_lat @ Mt via MFMA.
// Frag layouts (gfx950 16x16x32): A: row=l&15, cols (l>>4)*8+j;
// B: col=l&15, rows (l>>4)*8+j; C/D: col=l&15, row=(l>>4)*4+reg [m89].
// ---------------------------------------------------------------------------
__global__ __launch_bounds__(256, 2) void flash_mla2(
    const ushort_t* __restrict__ qfull,   // [NH][BT][576]
    const ushort_t* __restrict__ kfull,   // [BT][576]
    const ushort_t* __restrict__ ckvT,    // [B][512][1024]
    const ushort_t* __restrict__ Mtb,     // [2048][512]
    float*          __restrict__ out)     // [BT][2048]
{
    constexpr int KT = 32;
    constexpr int KS = 584;   // K-tile LDS stride (bf16): 1168B = 4 mod 32 banks
    constexpr int YS = 520;   // y-tile LDS stride
    constexpr int PS = 40;    // P LDS stride (80B rows, 16B-aligned)

    __shared__ ushort_t smem[4 * 16 * YS];          // union: Ks (32*KS) | y_s
    __shared__ ushort_t P_s[4][16][PS];

    ushort_t* Ks = smem;

    const int tid  = threadIdx.x;
    const int lane = tid & 63;
    const int w    = tid >> 6;
    const int l15  = lane & 15, l4 = lane >> 4;
    const int t0 = blockIdx.x * 64;
    const int h  = blockIdx.y;
    const int b  = blockIdx.z;
    const long bt0 = (long)b * Tn + t0;

    // Q A-frags in registers: 18 k-steps x 8 bf16
    bf16x8 qf[18];
    {
        const ushort_t* qrow = qfull + ((long)h * BT + bt0 + w * 16 + l15) * 576 + l4 * 8;
        #pragma unroll
        for (int ks = 0; ks < 18; ++ks)
            qf[ks] = *(const bf16x8*)(qrow + ks * 32);
    }

    f32x4 y[32];
    #pragma unroll
    for (int n = 0; n < 32; ++n) y[n] = (f32x4){0.f, 0.f, 0.f, 0.f};
    float mrun[4], lrun[4];
    #pragma unroll
    for (int j = 0; j < 4; ++j) { mrun[j] = -INFINITY; lrun[j] = 0.f; }

    const float SCL = ATT_SCALE * LOG2E;
    const int niter = (t0 + 64) / KT;

    for (int it = 0; it < niter; ++it) {
        const int s0 = it * KT;
        __syncthreads();                              // protect Ks vs prior reads
        {   // stage K tile [32][576] -> Ks[32][KS]
            const ushort_t* kbase = kfull + ((long)b * Tn + s0) * 576;
            #pragma unroll
            for (int c = 0; c < 9; ++c) {
                int chunk = tid + c * 256;            // 0..2303
                int row = chunk / 72, col8 = chunk % 72;
                *(uint4*)&Ks[row * KS + col8 * 8] =
                    *(const uint4*)&kbase[(long)row * 576 + col8 * 8];
            }
        }
        __syncthreads();

        // ---- S phase: two 16-col n-tiles
        f32x4 sa0 = (f32x4){0.f,0.f,0.f,0.f}, sa1 = (f32x4){0.f,0.f,0.f,0.f};
        #pragma unroll
        for (int ks = 0; ks < 18; ++ks) {
            bf16x8 kb0 = *(const bf16x8*)&Ks[(0 * 16 + l15) * KS + ks * 32 + l4 * 8];
            bf16x8 kb1 = *(const bf16x8*)&Ks[(1 * 16 + l15) * KS + ks * 32 + l4 * 8];
            sa0 = __builtin_amdgcn_mfma_f32_16x16x32_bf16(qf[ks], kb0, sa0, 0, 0, 0);
            sa1 = __builtin_amdgcn_mfma_f32_16x16x32_bf16(qf[ks], kb1, sa1, 0, 0, 0);
        }

        // ---- online softmax (log2 domain); rows = l4*4+j, cols = l15 (+16)
        const bool maskp = (s0 + KT > t0);
        float p0v[4], p1v[4], corr[4];
        #pragma unroll
        for (int j = 0; j < 4; ++j) {
            float s0v = sa0[j] * SCL;
            float s1v = sa1[j] * SCL;
            if (maskp) {
                int qrow = t0 + w * 16 + l4 * 4 + j;
                if (s0 + l15 > qrow)      s0v = -INFINITY;
                if (s0 + 16 + l15 > qrow) s1v = -INFINITY;
            }
            float tmax = fmaxf(s0v, s1v);
            tmax = fmaxf(tmax, __shfl_xor(tmax, 8));
            tmax = fmaxf(tmax, __shfl_xor(tmax, 4));
            tmax = fmaxf(tmax, __shfl_xor(tmax, 2));
            tmax = fmaxf(tmax, __shfl_xor(tmax, 1));
            float mnew = fmaxf(mrun[j], tmax);
            corr[j] = exp2f(mrun[j] - mnew);
            float p0 = exp2f(s0v - mnew);
            float p1 = exp2f(s1v - mnew);
            float ps = p0 + p1;
            ps += __shfl_xor(ps, 8);
            ps += __shfl_xor(ps, 4);
            ps += __shfl_xor(ps, 2);
            ps += __shfl_xor(ps, 1);
            lrun[j] = lrun[j] * corr[j] + ps;
            mrun[j] = mnew;
            p0v[j] = p0; p1v[j] = p1;
        }

        // P -> LDS (per-wave region; within-wave RAW handled by compiler)
        #pragma unroll
        for (int j = 0; j < 4; ++j) {
            P_s[w][l4 * 4 + j][l15]      = f2bf(p0v[j]);
            P_s[w][l4 * 4 + j][16 + l15] = f2bf(p1v[j]);
        }

        // rescale y
        #pragma unroll
        for (int n = 0; n < 32; ++n) {
            y[n][0] *= corr[0]; y[n][1] *= corr[1];
            y[n][2] *= corr[2]; y[n][3] *= corr[3];
        }

        // ---- PV phase: A = P (one frag covers all 32 k), B from ckvT (L2)
        bf16x8 pa = *(const bf16x8*)&P_s[w][l15][l4 * 8];
        const ushort_t* vtb = ckvT + (long)b * 512 * Tn + s0 + l4 * 8;
        #pragma unroll
        for (int n = 0; n < 32; ++n) {
            bf16x8 vb = *(const bf16x8*)&vtb[(long)(n * 16 + l15) * Tn];
            y[n] = __builtin_amdgcn_mfma_f32_16x16x32_bf16(pa, vb, y[n], 0, 0, 0);
        }
    }

    // ---- epilogue: y_lat -> LDS (bf16), then y_lat @ Mt_h^T via MFMA
    __syncthreads();                                  // all waves done with Ks
    float inv[4];
    #pragma unroll
    for (int j = 0; j < 4; ++j) inv[j] = 1.f / lrun[j];

    ushort_t* yw = smem + (w * 16) * YS;              // per-wave 16 x YS region
    #pragma unroll
    for (int n = 0; n < 32; ++n)
        #pragma unroll
        for (int j = 0; j < 4; ++j)
            yw[(l4 * 4 + j) * YS + n * 16 + l15] = f2bf(y[n][j] * inv[j]);

    bf16x8 ya[16];
    #pragma unroll
    for (int ks = 0; ks < 16; ++ks)
        ya[ks] = *(const bf16x8*)&yw[l15 * YS + ks * 32 + l4 * 8];

    const ushort_t* mtb = Mtb + (long)h * 128 * 512;
    #pragma unroll
    for (int nt = 0; nt < 8; ++nt) {
        f32x4 acc = (f32x4){0.f, 0.f, 0.f, 0.f};
        #pragma unroll
        for (int ks = 0; ks < 16; ++ks) {
            bf16x8 mb = *(const bf16x8*)&mtb[(long)(nt * 16 + l15) * 512 + ks * 32 + l4 * 8];
            acc = __builtin_amdgcn_mfma_f32_16x16x32_bf16(ya[ks], mb, acc, 0, 0, 0);
        }
        #pragma unroll
        for (int j = 0; j < 4; ++j)
            out[(bt0 + w * 16 + l4 * 4 + j) * Cn + h * 128 + nt * 16 + l15] = acc[j];
    }
}

// ---------------------------------------------------------------------------
extern "C" void kernel_launch(void* const* d_in, const int* in_sizes, int n_in,
                              void* d_out, int out_size, void* d_ws, size_t ws_size,
                              hipStream_t stream)
{
    (void)in_sizes; (void)n_in; (void)out_size; (void)ws_size;
    const float* x     = (const float*)d_in[0];
    const float* cosT  = (const float*)d_in[1];
    const float* sinT  = (const float*)d_in[2];
    const float* W_dq  = (const float*)d_in[3];
    const float* W_uq  = (const float*)d_in[4];
    const float* W_dkv = (const float*)d_in[5];
    const float* W_uk  = (const float*)d_in[6];
    const float* W_uv  = (const float*)d_in[7];
    const float* W_qr  = (const float*)d_in[8];
    const float* W_kr  = (const float*)d_in[9];
    const float* W_o   = (const float*)d_in[10];
    float* out = (float*)d_out;

    // workspace layout (~172 MB)
    float* c_q  = (float*)d_ws;                           // [BT][1536] f32
    float* krb  = c_q  + (long)BT * NLQ;                  // [BT][64]   f32
    float* qrb  = krb  + (long)BT * DHR;                  // [BT][1024] f32
    float* keff = qrb  + (long)BT * NH * DHR;             // [16][1536][512] f32
    ushort_t* Mtb   = (ushort_t*)(keff + (long)NH * NLQ * NLKV); // [2048][512] bf16
    ushort_t* qfull = Mtb   + (long)Cn * NLKV;            // [NH][BT][576] bf16
    ushort_t* kfull = qfull + (long)NH * BT * 576;        // [BT][576] bf16
    ushort_t* ckvT  = kfull + (long)BT * 576;             // [B][512][1024] bf16

    dim3 blk(256, 1, 1);

    // c_q = X @ W_dq^T   (f32)
    gemm_f32<128,128,16,8,8,true,float><<<dim3(NLQ/128, BT/128, 1), blk, 0, stream>>>(
        x, W_dq, c_q, Cn, Cn, Cn, NLQ, 0, 0, 0);
    // c_kv = X @ W_dkv^T -> bf16 into kfull cols 0..511 (ldc 576)
    gemm_f32<128,128,16,8,8,true,ushort_t><<<dim3(NLKV/128, BT/128, 1), blk, 0, stream>>>(
        x, W_dkv, kfull, Cn, Cn, Cn, 576, 0, 0, 0);
    // c_kr = X @ W_kr^T  (f32)
    gemm_f32<64,64,16,4,4,true,float><<<dim3(1, BT/64, 1), blk, 0, stream>>>(
        x, W_kr, krb, Cn, Cn, Cn, DHR, 0, 0, 0);
    rope_kr_kernel<<<dim3(BT*32/256), blk, 0, stream>>>(krb, kfull, cosT, sinT);
    // c_qr = c_q @ W_qr^T (f32)
    gemm_f32<128,128,16,8,8,true,float><<<dim3(NH*DHR/128, BT/128, 1), blk, 0, stream>>>(
        c_q, W_qr, qrb, NLQ, NLQ, NLQ, NH*DHR, 0, 0, 0);
    rope_qr_kernel<<<dim3(BT*512/256), blk, 0, stream>>>(qrb, qfull, cosT, sinT);
    // k_eff[h] (f32, batched 16)
    gemm_f32<128,128,16,8,8,false,float><<<dim3(NLKV/128, NLQ/128, NH), blk, 0, stream>>>(
        W_uq, W_uk, keff, HS, Cn, NLKV, NLKV,
        (long)HS, (long)HS*NLKV, (long)NLQ*NLKV);
    // Mt = W_o @ W_uv -> bf16
    gemm_f32<128,128,16,8,8,false,ushort_t><<<dim3(NLKV/128, Cn/128, 1), blk, 0, stream>>>(
        W_o, W_uv, Mtb, Cn, Cn, NLKV, NLKV, 0, 0, 0);
    // q_abs[h] = c_q @ k_eff[h] -> bf16 into qfull cols 0..511 (ldc 576)
    gemm_f32<128,128,16,8,8,false,ushort_t><<<dim3(NLKV/128, BT/128, NH), blk, 0, stream>>>(
        c_q, keff, qfull, NLQ, NLQ, NLKV, 576,
        0, (long)NLQ*NLKV, (long)BT*576);
    // ckvT[b][c][t]
    transpose_ckv<<<dim3(Bn*512*128/256), blk, 0, stream>>>(kfull, ckvT);
    // MFMA flash attention + fused output projection
    flash_mla2<<<dim3(Tn/64, NH, Bn), blk, 0, stream>>>(qfull, kfull, ckvT, Mtb, out);
}

// Round 3
// 1285.263 us; speedup vs baseline: 4.8391x; 2.4752x over previous
//
#include <hip/hip_runtime.h>
#include <type_traits>

typedef unsigned short ushort_t;
typedef unsigned int   uint_t;
typedef __attribute__((ext_vector_type(8))) short bf16x8;
typedef __attribute__((ext_vector_type(4))) float f32x4;

constexpr int Bn = 4, Tn = 1024, Cn = 2048, NH = 16, HS = 128;
constexpr int NLQ = 1536, NLKV = 512, DHR = 64;
constexpr int BT = Bn * Tn;
constexpr float ATT_SCALE = 0.07216878364870323f; // 1/sqrt(192)
constexpr float LOG2E = 1.4426950408889634f;

__device__ __forceinline__ ushort_t f2bf(float f) {
    uint_t u = __float_as_uint(f);
    u += 0x7fffu + ((u >> 16) & 1u);   // RNE
    return (ushort_t)(u >> 16);
}

__device__ __forceinline__ void gload_lds16(const void* g, void* l) {
    __builtin_amdgcn_global_load_lds(
        (__attribute__((address_space(1))) void*)g,
        (__attribute__((address_space(3))) void*)l, 16, 0, 0);
}

// ---------------------------------------------------------------------------
// f32 -> bf16 conversion (vectorized, 8/thread). n must be multiple of 2048.
// ---------------------------------------------------------------------------
__global__ void cvt_bf16(const float* __restrict__ in, ushort_t* __restrict__ out) {
    long i = ((long)blockIdx.x * 256 + threadIdx.x) * 8;
    float4 a = *(const float4*)&in[i];
    float4 b = *(const float4*)&in[i + 4];
    ushort_t p[8] = {f2bf(a.x), f2bf(a.y), f2bf(a.z), f2bf(a.w),
                     f2bf(b.x), f2bf(b.y), f2bf(b.z), f2bf(b.w)};
    *(uint4*)&out[i] = *(const uint4*)p;
}

// ---------------------------------------------------------------------------
// Transpose+convert [2048][512] f32 -> [512][2048] bf16 (z=0: W_uk, z=1: W_uv)
// ---------------------------------------------------------------------------
__global__ __launch_bounds__(256) void transcvt_bf16(
    const float* __restrict__ A, ushort_t* __restrict__ At,
    const float* __restrict__ Bp, ushort_t* __restrict__ Bt)
{
    __shared__ float tile[64][65];
    const float* in = blockIdx.z ? Bp : A;
    ushort_t* out   = blockIdx.z ? Bt : At;
    const int k0 = blockIdx.x * 64, c0 = blockIdx.y * 64;
    const int t = threadIdx.x;
    #pragma unroll
    for (int i = 0; i < 4; ++i) {
        int idx = t + i * 256;
        int r = idx >> 4, c4 = idx & 15;
        float4 v = *(const float4*)&in[(long)(c0 + r) * 512 + k0 + c4 * 4];
        tile[r][c4 * 4 + 0] = v.x; tile[r][c4 * 4 + 1] = v.y;
        tile[r][c4 * 4 + 2] = v.z; tile[r][c4 * 4 + 3] = v.w;
    }
    __syncthreads();
    #pragma unroll
    for (int i = 0; i < 4; ++i) {
        int idx = t + i * 256;
        int kr = idx >> 4, c4 = idx & 15;
        ushort_t p[4];
        #pragma unroll
        for (int j = 0; j < 4; ++j) p[j] = f2bf(tile[c4 * 4 + j][kr]);
        *(uint2*)&out[(long)(k0 + kr) * 2048 + c0 + c4 * 4] = *(const uint2*)p;
    }
}

// ---------------------------------------------------------------------------
// bf16 MFMA GEMM (m97 structure): C[M,N] = A[M,K] @ B^T, A [M][lda], B [N][ldb]
// (both NT), bf16 out. 128x128 tile, BK=32, 4 waves (2x2 of 64x64), linear LDS
// staged via global_load_lds width 16, 2-barrier loop.
// Frag layouts (16x16x32): A row=l&15 k=(l>>4)*8+j; B col=l&15 k=(l>>4)*8+j;
// C/D col=l&15 row=(l>>4)*4+reg [m89].
// ---------------------------------------------------------------------------
__global__ __launch_bounds__(256, 2) void gemm_bf16(
    const ushort_t* __restrict__ A, const ushort_t* __restrict__ B,
    ushort_t* __restrict__ C,
    int K, int lda, int ldb, int ldc, long sA, long sB, long sC)
{
    constexpr int BK = 32;
    __shared__ ushort_t As[128 * BK];
    __shared__ ushort_t Bs[128 * BK];

    const int tid  = threadIdx.x;
    const int lane = tid & 63;
    const int w    = tid >> 6;
    const int l15 = lane & 15, l4 = lane >> 4;
    const int wr = w >> 1, wc = w & 1;
    const int m0 = blockIdx.y * 128, n0 = blockIdx.x * 128;
    const ushort_t* Ab = A + (long)blockIdx.z * sA;
    const ushort_t* Bb = B + (long)blockIdx.z * sB;
    ushort_t*       Cb = C + (long)blockIdx.z * sC;

    const int srow = lane >> 2;          // 0..15
    const int scol = (lane & 3) * 8;     // octet within 32-col row

    f32x4 acc[4][4];
    #pragma unroll
    for (int m = 0; m < 4; ++m)
        #pragma unroll
        for (int n = 0; n < 4; ++n) acc[m][n] = (f32x4){0.f, 0.f, 0.f, 0.f};

    for (int k0 = 0; k0 < K; k0 += BK) {
        #pragma unroll
        for (int i = 0; i < 2; ++i) {
            int r = w * 32 + i * 16;     // 16 rows per wave-instr
            gload_lds16(Ab + (long)(m0 + r + srow) * lda + k0 + scol, &As[r * BK]);
            gload_lds16(Bb + (long)(n0 + r + srow) * ldb + k0 + scol, &Bs[r * BK]);
        }
        __syncthreads();                  // drains vmcnt -> LDS ready

        bf16x8 af[4], bfv[4];
        #pragma unroll
        for (int m = 0; m < 4; ++m)
            af[m] = *(const bf16x8*)&As[(wr * 64 + m * 16 + l15) * BK + l4 * 8];
        #pragma unroll
        for (int n = 0; n < 4; ++n)
            bfv[n] = *(const bf16x8*)&Bs[(wc * 64 + n * 16 + l15) * BK + l4 * 8];
        #pragma unroll
        for (int m = 0; m < 4; ++m)
            #pragma unroll
            for (int n = 0; n < 4; ++n)
                acc[m][n] = __builtin_amdgcn_mfma_f32_16x16x32_bf16(af[m], bfv[n], acc[m][n], 0, 0, 0);
        __syncthreads();                  // all reads done before next stage
    }

    #pragma unroll
    for (int m = 0; m < 4; ++m)
        #pragma unroll
        for (int j = 0; j < 4; ++j) {
            long row = m0 + wr * 64 + m * 16 + l4 * 4 + j;
            #pragma unroll
            for (int n = 0; n < 4; ++n)
                Cb[row * ldc + n0 + wc * 64 + n * 16 + l15] = f2bf(acc[m][n][j]);
        }
}

// ---------------------------------------------------------------------------
// Tiled f32 GEMM (kept only for c_kr: M=4096, N=64, K=2048)
// ---------------------------------------------------------------------------
template<int BM, int BN, int BK, int TM, int TN, bool BTRANS, typename OutT>
__global__ __launch_bounds__(256) void gemm_f32(
    const float* __restrict__ A, const float* __restrict__ Bp, OutT* __restrict__ Cp,
    int K, int lda, int ldb, int ldc, long sA, long sB, long sC)
{
    static_assert(BK == 16, "loader assumes BK=16");
    static_assert((BM / TM) * (BN / TN) == 256, "256 threads");
    const float* Ab = A  + (long)blockIdx.z * sA;
    const float* Bx = Bp + (long)blockIdx.z * sB;
    OutT*        Cb = Cp + (long)blockIdx.z * sC;

    __shared__ float As[BK][BM + 4];
    __shared__ float Bs[BK][BN + 4];

    const int tid = threadIdx.x;
    const int tx = tid % (BN / TN);
    const int ty = tid / (BN / TN);
    const int m0 = blockIdx.y * BM, n0 = blockIdx.x * BN;

    float acc[TM][TN] = {};

    for (int k0 = 0; k0 < K; k0 += BK) {
        #pragma unroll
        for (int i = 0; i < BM * BK / 1024; ++i) {
            int chunk = tid + i * 256;
            int row = chunk >> 2;
            int kq  = chunk & 3;
            float4 v = *(const float4*)&Ab[(long)(m0 + row) * lda + k0 + kq * 4];
            As[kq * 4 + 0][row] = v.x; As[kq * 4 + 1][row] = v.y;
            As[kq * 4 + 2][row] = v.z; As[kq * 4 + 3][row] = v.w;
        }
        if constexpr (BTRANS) {
            #pragma unroll
            for (int i = 0; i < BN * BK / 1024; ++i) {
                int chunk = tid + i * 256;
                int row = chunk >> 2;
                int kq  = chunk & 3;
                float4 v = *(const float4*)&Bx[(long)(n0 + row) * ldb + k0 + kq * 4];
                Bs[kq * 4 + 0][row] = v.x; Bs[kq * 4 + 1][row] = v.y;
                Bs[kq * 4 + 2][row] = v.z; Bs[kq * 4 + 3][row] = v.w;
            }
        } else {
            #pragma unroll
            for (int i = 0; i < BN * BK / 1024; ++i) {
                int chunk = tid + i * 256;
                int krow = chunk / (BN / 4);
                int nq   = chunk % (BN / 4);
                *(float4*)&Bs[krow][nq * 4] =
                    *(const float4*)&Bx[(long)(k0 + krow) * ldb + n0 + nq * 4];
            }
        }
        __syncthreads();

        #pragma unroll
        for (int kk = 0; kk < BK; ++kk) {
            float a[TM], bv[TN];
            #pragma unroll
            for (int i = 0; i < TM; ++i) a[i] = As[kk][ty * TM + i];
            #pragma unroll
            for (int j = 0; j < TN; ++j) {
                int half = j / (TN / 2), jj = j % (TN / 2);
                bv[j] = Bs[kk][half * (BN / 2) + tx * (TN / 2) + jj];
            }
            #pragma unroll
            for (int i = 0; i < TM; ++i)
                #pragma unroll
                for (int j = 0; j < TN; ++j)
                    acc[i][j] += a[i] * bv[j];
        }
        __syncthreads();
    }

    #pragma unroll
    for (int i = 0; i < TM; ++i) {
        long rbase = (long)(m0 + ty * TM + i) * ldc + n0;
        #pragma unroll
        for (int half = 0; half < 2; ++half) {
            long cbase = rbase + half * (BN / 2) + tx * (TN / 2);
            #pragma unroll
            for (int jj = 0; jj < TN / 2; ++jj)
                Cb[cbase + jj] = acc[i][half * (TN / 2) + jj];
        }
    }
}

// ---------------------------------------------------------------------------
// RoPE kernels
// ---------------------------------------------------------------------------
__global__ void rope_kr_kernel(const float* __restrict__ krb, ushort_t* __restrict__ kfull,
                               const float* __restrict__ cosT, const float* __restrict__ sinT) {
    int p = blockIdx.x * 256 + threadIdx.x;          // BT*32 pairs
    if (p >= BT * 32) return;
    int bt = p >> 5, i = p & 31;
    int t = bt & (Tn - 1);
    float c = cosT[t * 32 + i], s = sinT[t * 32 + i];
    float re = krb[bt * 64 + 2 * i], im = krb[bt * 64 + 2 * i + 1];
    float o0 = re * c - im * s, o1 = re * s + im * c;
    uint_t u = (uint_t)f2bf(o0) | ((uint_t)f2bf(o1) << 16);
    *(uint_t*)&kfull[(long)bt * 576 + 512 + 2 * i] = u;
}

__global__ void rope_qr_kernel(const ushort_t* __restrict__ qrb, ushort_t* __restrict__ qfull,
                               const float* __restrict__ cosT, const float* __restrict__ sinT) {
    int p = blockIdx.x * 256 + threadIdx.x;          // BT*NH*32 pairs
    if (p >= BT * 512) return;
    int bt = p >> 9, rem = p & 511;
    int hh = rem >> 5, i = rem & 31;
    int t = bt & (Tn - 1);
    float c = cosT[t * 32 + i], s = sinT[t * 32 + i];
    uint_t u = *(const uint_t*)&qrb[(long)bt * 1024 + hh * 64 + 2 * i];
    float re = __uint_as_float(u << 16);
    float im = __uint_as_float(u & 0xffff0000u);
    float o0 = re * c - im * s, o1 = re * s + im * c;
    uint_t o = (uint_t)f2bf(o0) | ((uint_t)f2bf(o1) << 16);
    *(uint_t*)&qfull[((long)hh * BT + bt) * 576 + 512 + 2 * i] = o;
}

// ---------------------------------------------------------------------------
// Transpose c_kv (cols 0..511 of kfull) into ckvT[b][c][t] (bf16)
// ---------------------------------------------------------------------------
__global__ void transpose_ckv(const ushort_t* __restrict__ kfull, ushort_t* __restrict__ ckvT) {
    int idx = blockIdx.x * 256 + threadIdx.x;        // 4*128*512
    int c = idx & 511, rest = idx >> 9;
    int t8 = rest & 127, b = rest >> 7;
    ushort_t v[8];
    #pragma unroll
    for (int j = 0; j < 8; ++j)
        v[j] = kfull[((long)b * Tn + t8 * 8 + j) * 576 + c];
    *(uint4*)&ckvT[((long)b * 512 + c) * Tn + t8 * 8] = *(const uint4*)v;
}

// ---------------------------------------------------------------------------
// MFMA flash MLA (unchanged from round 2)
// ---------------------------------------------------------------------------
__global__ __launch_bounds__(256, 2) void flash_mla2(
    const ushort_t* __restrict__ qfull,   // [NH][BT][576]
    const ushort_t* __restrict__ kfull,   // [BT][576]
    const ushort_t* __restrict__ ckvT,    // [B][512][1024]
    const ushort_t* __restrict__ Mtb,     // [2048][512]
    float*          __restrict__ out)     // [BT][2048]
{
    constexpr int KT = 32;
    constexpr int KS = 584;
    constexpr int YS = 520;
    constexpr int PS = 40;

    __shared__ ushort_t smem[4 * 16 * YS];
    __shared__ ushort_t P_s[4][16][PS];

    ushort_t* Ks = smem;

    const int tid  = threadIdx.x;
    const int lane = tid & 63;
    const int w    = tid >> 6;
    const int l15  = lane & 15, l4 = lane >> 4;
    const int t0 = blockIdx.x * 64;
    const int h  = blockIdx.y;
    const int b  = blockIdx.z;
    const long bt0 = (long)b * Tn + t0;

    bf16x8 qf[18];
    {
        const ushort_t* qrow = qfull + ((long)h * BT + bt0 + w * 16 + l15) * 576 + l4 * 8;
        #pragma unroll
        for (int ks = 0; ks < 18; ++ks)
            qf[ks] = *(const bf16x8*)(qrow + ks * 32);
    }

    f32x4 y[32];
    #pragma unroll
    for (int n = 0; n < 32; ++n) y[n] = (f32x4){0.f, 0.f, 0.f, 0.f};
    float mrun[4], lrun[4];
    #pragma unroll
    for (int j = 0; j < 4; ++j) { mrun[j] = -INFINITY; lrun[j] = 0.f; }

    const float SCL = ATT_SCALE * LOG2E;
    const int niter = (t0 + 64) / KT;

    for (int it = 0; it < niter; ++it) {
        const int s0 = it * KT;
        __syncthreads();
        {
            const ushort_t* kbase = kfull + ((long)b * Tn + s0) * 576;
            #pragma unroll
            for (int c = 0; c < 9; ++c) {
                int chunk = tid + c * 256;
                int row = chunk / 72, col8 = chunk % 72;
                *(uint4*)&Ks[row * KS + col8 * 8] =
                    *(const uint4*)&kbase[(long)row * 576 + col8 * 8];
            }
        }
        __syncthreads();

        f32x4 sa0 = (f32x4){0.f,0.f,0.f,0.f}, sa1 = (f32x4){0.f,0.f,0.f,0.f};
        #pragma unroll
        for (int ks = 0; ks < 18; ++ks) {
            bf16x8 kb0 = *(const bf16x8*)&Ks[(0 * 16 + l15) * KS + ks * 32 + l4 * 8];
            bf16x8 kb1 = *(const bf16x8*)&Ks[(1 * 16 + l15) * KS + ks * 32 + l4 * 8];
            sa0 = __builtin_amdgcn_mfma_f32_16x16x32_bf16(qf[ks], kb0, sa0, 0, 0, 0);
            sa1 = __builtin_amdgcn_mfma_f32_16x16x32_bf16(qf[ks], kb1, sa1, 0, 0, 0);
        }

        const bool maskp = (s0 + KT > t0);
        float p0v[4], p1v[4], corr[4];
        #pragma unroll
        for (int j = 0; j < 4; ++j) {
            float s0v = sa0[j] * SCL;
            float s1v = sa1[j] * SCL;
            if (maskp) {
                int qrow = t0 + w * 16 + l4 * 4 + j;
                if (s0 + l15 > qrow)      s0v = -INFINITY;
                if (s0 + 16 + l15 > qrow) s1v = -INFINITY;
            }
            float tmax = fmaxf(s0v, s1v);
            tmax = fmaxf(tmax, __shfl_xor(tmax, 8));
            tmax = fmaxf(tmax, __shfl_xor(tmax, 4));
            tmax = fmaxf(tmax, __shfl_xor(tmax, 2));
            tmax = fmaxf(tmax, __shfl_xor(tmax, 1));
            float mnew = fmaxf(mrun[j], tmax);
            corr[j] = exp2f(mrun[j] - mnew);
            float p0 = exp2f(s0v - mnew);
            float p1 = exp2f(s1v - mnew);
            float ps = p0 + p1;
            ps += __shfl_xor(ps, 8);
            ps += __shfl_xor(ps, 4);
            ps += __shfl_xor(ps, 2);
            ps += __shfl_xor(ps, 1);
            lrun[j] = lrun[j] * corr[j] + ps;
            mrun[j] = mnew;
            p0v[j] = p0; p1v[j] = p1;
        }

        #pragma unroll
        for (int j = 0; j < 4; ++j) {
            P_s[w][l4 * 4 + j][l15]      = f2bf(p0v[j]);
            P_s[w][l4 * 4 + j][16 + l15] = f2bf(p1v[j]);
        }

        #pragma unroll
        for (int n = 0; n < 32; ++n) {
            y[n][0] *= corr[0]; y[n][1] *= corr[1];
            y[n][2] *= corr[2]; y[n][3] *= corr[3];
        }

        bf16x8 pa = *(const bf16x8*)&P_s[w][l15][l4 * 8];
        const ushort_t* vtb = ckvT + (long)b * 512 * Tn + s0 + l4 * 8;
        #pragma unroll
        for (int n = 0; n < 32; ++n) {
            bf16x8 vb = *(const bf16x8*)&vtb[(long)(n * 16 + l15) * Tn];
            y[n] = __builtin_amdgcn_mfma_f32_16x16x32_bf16(pa, vb, y[n], 0, 0, 0);
        }
    }

    __syncthreads();
    float inv[4];
    #pragma unroll
    for (int j = 0; j < 4; ++j) inv[j] = 1.f / lrun[j];

    ushort_t* yw = smem + (w * 16) * YS;
    #pragma unroll
    for (int n = 0; n < 32; ++n)
        #pragma unroll
        for (int j = 0; j < 4; ++j)
            yw[(l4 * 4 + j) * YS + n * 16 + l15] = f2bf(y[n][j] * inv[j]);

    bf16x8 ya[16];
    #pragma unroll
    for (int ks = 0; ks < 16; ++ks)
        ya[ks] = *(const bf16x8*)&yw[l15 * YS + ks * 32 + l4 * 8];

    const ushort_t* mtb = Mtb + (long)h * 128 * 512;
    #pragma unroll
    for (int nt = 0; nt < 8; ++nt) {
        f32x4 acc = (f32x4){0.f, 0.f, 0.f, 0.f};
        #pragma unroll
        for (int ks = 0; ks < 16; ++ks) {
            bf16x8 mb = *(const bf16x8*)&mtb[(long)(nt * 16 + l15) * 512 + ks * 32 + l4 * 8];
            acc = __builtin_amdgcn_mfma_f32_16x16x32_bf16(ya[ks], mb, acc, 0, 0, 0);
        }
        #pragma unroll
        for (int j = 0; j < 4; ++j)
            out[(bt0 + w * 16 + l4 * 4 + j) * Cn + h * 128 + nt * 16 + l15] = acc[j];
    }
}

// ---------------------------------------------------------------------------
extern "C" void kernel_launch(void* const* d_in, const int* in_sizes, int n_in,
                              void* d_out, int out_size, void* d_ws, size_t ws_size,
                              hipStream_t stream)
{
    (void)in_sizes; (void)n_in; (void)out_size; (void)ws_size;
    const float* x     = (const float*)d_in[0];
    const float* cosT  = (const float*)d_in[1];
    const float* sinT  = (const float*)d_in[2];
    const float* W_dq  = (const float*)d_in[3];   // [1536][2048]
    const float* W_uq  = (const float*)d_in[4];   // flat [2048*1536]
    const float* W_dkv = (const float*)d_in[5];   // [512][2048]
    const float* W_uk  = (const float*)d_in[6];   // [2048][512]
    const float* W_uv  = (const float*)d_in[7];   // [2048][512]
    const float* W_qr  = (const float*)d_in[8];   // [1024][1536]
    const float* W_kr  = (const float*)d_in[9];   // [64][2048]
    const float* W_o   = (const float*)d_in[10];  // [2048][2048]
    float* out = (float*)d_out;

    // workspace layout (~181 MB, all bf16 except krb)
    ushort_t* xb     = (ushort_t*)d_ws;                 // 8388608
    ushort_t* Wdq_b  = xb     + 8388608;                // 3145728
    ushort_t* Wuq_b  = Wdq_b  + 3145728;                // 3145728
    ushort_t* Wqr_b  = Wuq_b  + 3145728;                // 1572864
    ushort_t* Wo_b   = Wqr_b  + 1572864;                // 4194304
    ushort_t* Wdkv_b = Wo_b   + 4194304;                // 1048576
    ushort_t* WukT_b = Wdkv_b + 1048576;                // 1048576  [512][2048]
    ushort_t* WuvT_b = WukT_b + 1048576;                // 1048576  [512][2048]
    ushort_t* cq_b   = WuvT_b + 1048576;                // 6291456  [4096][1536]
    ushort_t* qr_b   = cq_b   + 6291456;                // 4194304  [4096][1024]
    ushort_t* keffT  = qr_b   + 4194304;                // 12582912 [16][512][1536]
    ushort_t* Mtb    = keffT  + 12582912;               // 1048576  [2048][512]
    ushort_t* qfull  = Mtb    + 1048576;                // 37748736 [16][4096][576]
    ushort_t* kfull  = qfull  + 37748736;               // 2359296  [4096][576]
    ushort_t* ckvT   = kfull  + 2359296;                // 2097152  [4][512][1024]
    float*    krb    = (float*)(ckvT + 2097152);        // [4096][64] f32

    dim3 blk(256, 1, 1);

    // ---- bf16 conversions ----
    cvt_bf16<<<dim3(4096), blk, 0, stream>>>(x, xb);
    cvt_bf16<<<dim3(1536), blk, 0, stream>>>(W_dq, Wdq_b);
    cvt_bf16<<<dim3(1536), blk, 0, stream>>>(W_uq, Wuq_b);
    cvt_bf16<<<dim3(768),  blk, 0, stream>>>(W_qr, Wqr_b);
    cvt_bf16<<<dim3(2048), blk, 0, stream>>>(W_o, Wo_b);
    cvt_bf16<<<dim3(512),  blk, 0, stream>>>(W_dkv, Wdkv_b);
    transcvt_bf16<<<dim3(8, 32, 2), blk, 0, stream>>>(W_uk, WukT_b, W_uv, WuvT_b);

    // ---- MFMA GEMMs (all NT) ----
    // c_q = xb @ Wdq_b^T          M=4096 N=1536 K=2048
    gemm_bf16<<<dim3(12, 32, 1), blk, 0, stream>>>(
        xb, Wdq_b, cq_b, Cn, Cn, Cn, NLQ, 0, 0, 0);
    // c_kv -> kfull[:, :512]      M=4096 N=512 K=2048, ldc 576
    gemm_bf16<<<dim3(4, 32, 1), blk, 0, stream>>>(
        xb, Wdkv_b, kfull, Cn, Cn, Cn, 576, 0, 0, 0);
    // c_kr (f32, tiny)            M=4096 N=64 K=2048
    gemm_f32<64,64,16,4,4,true,float><<<dim3(1, BT/64, 1), blk, 0, stream>>>(
        x, W_kr, krb, Cn, Cn, Cn, DHR, 0, 0, 0);
    rope_kr_kernel<<<dim3(BT*32/256), blk, 0, stream>>>(krb, kfull, cosT, sinT);
    // c_qr = cq_b @ Wqr_b^T       M=4096 N=1024 K=1536 (bf16 out)
    gemm_bf16<<<dim3(8, 32, 1), blk, 0, stream>>>(
        cq_b, Wqr_b, qr_b, NLQ, NLQ, NLQ, NH*DHR, 0, 0, 0);
    rope_qr_kernel<<<dim3(BT*512/256), blk, 0, stream>>>(qr_b, qfull, cosT, sinT);
    // keffT[h] = WukT_h @ Wuq_h^T  M=512 N=1536 K=128, batched 16
    gemm_bf16<<<dim3(12, 4, NH), blk, 0, stream>>>(
        WukT_b, Wuq_b, keffT, HS, Cn, Cn, NLQ, 128, 128, (long)NLKV*NLQ);
    // Mt = Wo_b @ WuvT_b^T        M=2048 N=512 K=2048
    gemm_bf16<<<dim3(4, 16, 1), blk, 0, stream>>>(
        Wo_b, WuvT_b, Mtb, Cn, Cn, Cn, NLKV, 0, 0, 0);
    // qabs[h] = cq_b @ keffT[h]^T  M=4096 N=512 K=1536, batched 16, into qfull
    gemm_bf16<<<dim3(4, 32, NH), blk, 0, stream>>>(
        cq_b, keffT, qfull, NLQ, NLQ, NLQ, 576,
        0, (long)NLKV*NLQ, (long)BT*576);
    // ckvT[b][c][t]
    transpose_ckv<<<dim3(Bn*512*128/256), blk, 0, stream>>>(kfull, ckvT);
    // flash attention + fused output projection
    flash_mla2<<<dim3(Tn/64, NH, Bn), blk, 0, stream>>>(qfull, kfull, ckvT, Mtb, out);
}